// Round 1
// baseline (567.530 us; speedup 1.0000x reference)
//
#include <hip/hip_runtime.h>

#define DD 128

// ---------------- transpose 128x128: Wt[k][j] = W[j][k] ----------------
__global__ void transpose128(const float* __restrict__ W, float* __restrict__ Wt) {
    int idx = blockIdx.x * 256 + threadIdx.x;   // 0..16383
    int j = idx >> 7;
    int k = idx & 127;
    Wt[k * 128 + j] = W[idx];
}

// ---------------- histogram of dst ----------------
__global__ void hist_kernel(const int* __restrict__ dst, int* __restrict__ deg, int E) {
    int e = blockIdx.x * 256 + threadIdx.x;
    if (e < E) atomicAdd(&deg[dst[e]], 1);
}

// ---------------- single-block scan: rowptr (excl->incl) + cursor ----------------
__global__ __launch_bounds__(1024) void scan_kernel(const int* __restrict__ deg,
                                                    int* __restrict__ rowptr,
                                                    int* __restrict__ cursor, int n) {
    __shared__ int s[1024];
    __shared__ int carry_s;
    int t = threadIdx.x;
    if (t == 0) { carry_s = 0; rowptr[0] = 0; }
    __syncthreads();
    for (int base = 0; base < n; base += 8192) {
        int i0 = base + t * 8;
        int v[8];
        int sum = 0;
#pragma unroll
        for (int u = 0; u < 8; ++u) {
            v[u] = (i0 + u < n) ? deg[i0 + u] : 0;
            sum += v[u];
        }
        s[t] = sum;
        __syncthreads();
        for (int off = 1; off < 1024; off <<= 1) {
            int x = (t >= off) ? s[t - off] : 0;
            __syncthreads();
            s[t] += x;
            __syncthreads();
        }
        int carryv = carry_s;
        int run = s[t] - sum + carryv;   // exclusive prefix for this thread's first elem
#pragma unroll
        for (int u = 0; u < 8; ++u) {
            int i = i0 + u;
            if (i < n) {
                cursor[i] = run;
                run += v[u];
                rowptr[i + 1] = run;
            }
        }
        __syncthreads();
        if (t == 1023) carry_s = s[1023] + carryv;
        __syncthreads();
    }
}

// ---------------- scatter edges into CSR buckets (store src id) ----------------
__global__ void scatter_kernel(const int* __restrict__ src, const int* __restrict__ dst,
                               int* __restrict__ cursor, int* __restrict__ csr_src, int E) {
    int e = blockIdx.x * 256 + threadIdx.x;
    if (e < E) {
        int p = atomicAdd(&cursor[dst[e]], 1);
        csr_src[p] = src[e];
    }
}

// ---------------- segment max gather: one wave per dst node ----------------
__global__ void segmax_kernel(const float* __restrict__ m, const int* __restrict__ rowptr,
                              const int* __restrict__ csr_src, float* __restrict__ agg, int n) {
    int node = blockIdx.x * 4 + (threadIdx.x >> 6);
    if (node >= n) return;
    int lane = threadIdx.x & 63;
    int beg = rowptr[node];
    int end = rowptr[node + 1];
    float mx0 = 0.f, mx1 = 0.f;   // relu'd inputs are >= 0; empty segment -> 0 (matches ref)
    const float* mp = m + lane * 2;
    for (int e = beg; e < end; ++e) {
        int s = csr_src[e];
        float2 v = *(const float2*)(mp + (size_t)s * DD);
        mx0 = fmaxf(mx0, v.x);
        mx1 = fmaxf(mx1, v.y);
    }
    float2 o;
    o.x = mx0;
    o.y = mx1;
    *(float2*)(agg + (size_t)node * DD + lane * 2) = o;
}

// ---------------- GEMM: out = A @ W^T (+ G @ W2^T) + bias, with epilogues ----------------
__device__ __forceinline__ void stage_rows(float* __restrict__ Sh, const float* __restrict__ A,
                                           int row0, int nrows, int tid) {
#pragma unroll
    for (int it = 0; it < 8; ++it) {
        int idx = it * 512 + tid;
        int r = idx >> 5;
        int c4 = (idx & 31) << 2;
        float4 v = make_float4(0.f, 0.f, 0.f, 0.f);
        if (row0 + r < nrows) v = *(const float4*)(A + (size_t)(row0 + r) * DD + c4);
        *(float4*)(Sh + r * DD + c4) = v;
    }
}

__device__ __forceinline__ void stage_w(float* __restrict__ Sh, const float* __restrict__ Wt, int tid) {
#pragma unroll
    for (int it = 0; it < 8; ++it) {
        int idx = it * 512 + tid;
        *(float4*)(Sh + idx * 4) = *(const float4*)(Wt + idx * 4);
    }
}

__device__ __forceinline__ void compute_tile(float acc[8][4], const float* __restrict__ As,
                                             const float* __restrict__ Ws, int tr, int tc) {
#pragma unroll 4
    for (int k4 = 0; k4 < 32; ++k4) {
        float4 b0 = *(const float4*)(Ws + (k4 * 4 + 0) * DD + tc * 4);
        float4 b1 = *(const float4*)(Ws + (k4 * 4 + 1) * DD + tc * 4);
        float4 b2 = *(const float4*)(Ws + (k4 * 4 + 2) * DD + tc * 4);
        float4 b3 = *(const float4*)(Ws + (k4 * 4 + 3) * DD + tc * 4);
#pragma unroll
        for (int rr = 0; rr < 8; ++rr) {
            float4 a = *(const float4*)(As + (tr * 8 + rr) * DD + k4 * 4);
            acc[rr][0] = fmaf(a.w, b3.x, fmaf(a.z, b2.x, fmaf(a.y, b1.x, fmaf(a.x, b0.x, acc[rr][0]))));
            acc[rr][1] = fmaf(a.w, b3.y, fmaf(a.z, b2.y, fmaf(a.y, b1.y, fmaf(a.x, b0.y, acc[rr][1]))));
            acc[rr][2] = fmaf(a.w, b3.z, fmaf(a.z, b2.z, fmaf(a.y, b1.z, fmaf(a.x, b0.z, acc[rr][2]))));
            acc[rr][3] = fmaf(a.w, b3.w, fmaf(a.z, b2.w, fmaf(a.y, b1.w, fmaf(a.x, b0.w, acc[rr][3]))));
        }
    }
}

// EPI: 0 = none, 1 = relu, 2 = relu + row L2 normalize
template <int EPI>
__global__ __launch_bounds__(512, 1) void gemm_kernel(const float* __restrict__ A,
                                                      const float* __restrict__ WtA,
                                                      const float* __restrict__ G,
                                                      const float* __restrict__ WtG,
                                                      const float* __restrict__ bias,
                                                      float* __restrict__ out, int nrows) {
    __shared__ float As[DD * DD];   // 64 KB
    __shared__ float Ws[DD * DD];   // 64 KB
    int tid = threadIdx.x;
    int row0 = blockIdx.x * DD;
    int tr = tid >> 5;
    int tc = tid & 31;

    float acc[8][4];
    float4 bv = *(const float4*)(bias + tc * 4);
#pragma unroll
    for (int rr = 0; rr < 8; ++rr) {
        acc[rr][0] = bv.x; acc[rr][1] = bv.y; acc[rr][2] = bv.z; acc[rr][3] = bv.w;
    }

    stage_rows(As, A, row0, nrows, tid);
    stage_w(Ws, WtA, tid);
    __syncthreads();
    compute_tile(acc, As, Ws, tr, tc);

    if (G != nullptr) {
        __syncthreads();
        stage_rows(As, G, row0, nrows, tid);
        stage_w(Ws, WtG, tid);
        __syncthreads();
        compute_tile(acc, As, Ws, tr, tc);
    }

#pragma unroll
    for (int rr = 0; rr < 8; ++rr) {
        int row = row0 + tr * 8 + rr;
        if (row >= nrows) continue;   // uniform within each 32-lane group
        float4 v = make_float4(acc[rr][0], acc[rr][1], acc[rr][2], acc[rr][3]);
        if (EPI >= 1) {
            v.x = fmaxf(v.x, 0.f); v.y = fmaxf(v.y, 0.f);
            v.z = fmaxf(v.z, 0.f); v.w = fmaxf(v.w, 0.f);
        }
        if (EPI == 2) {
            float s = v.x * v.x + v.y * v.y + v.z * v.z + v.w * v.w;
            s += __shfl_xor(s, 16);
            s += __shfl_xor(s, 8);
            s += __shfl_xor(s, 4);
            s += __shfl_xor(s, 2);
            s += __shfl_xor(s, 1);
            float scale = 1.0f / fmaxf(sqrtf(s), 1e-12f);
            v.x *= scale; v.y *= scale; v.z *= scale; v.w *= scale;
        }
        *(float4*)(out + (size_t)row * DD + tc * 4) = v;
    }
}

static inline size_t align16(size_t x) { return (x + 15) & ~(size_t)15; }

extern "C" void kernel_launch(void* const* d_in, const int* in_sizes, int n_in,
                              void* d_out, int out_size, void* d_ws, size_t ws_size,
                              hipStream_t stream) {
    const float* x    = (const float*)d_in[0];
    const int* esrc   = (const int*)d_in[1];
    const int* edst   = (const int*)d_in[2];
    const float* Wm[6];
    for (int i = 0; i < 6; ++i) Wm[i] = (const float*)d_in[3 + i];
    const float* bpool0 = (const float*)d_in[9];
    const float* b0     = (const float*)d_in[10];
    const float* bpool1 = (const float*)d_in[11];
    const float* b1     = (const float*)d_in[12];

    int N = in_sizes[0] / DD;
    int E = in_sizes[1];

    // workspace layout
    char* p = (char*)d_ws;
    float* Wt = (float*)p;      p += align16((size_t)6 * 16384 * 4);
    float* m  = (float*)p;      p += align16((size_t)N * DD * 4);
    float* agg = (float*)p;     p += align16((size_t)N * DD * 4);
    int* deg   = (int*)p;       p += align16((size_t)N * 4);
    int* rowptr = (int*)p;      p += align16((size_t)(N + 1) * 4);
    int* cursor = (int*)p;      p += align16((size_t)N * 4);
    int* csr_src = (int*)p;     p += align16((size_t)E * 4);

    float* out_h   = (float*)d_out;                 // output 0: final layer
    float* out_enc = (float*)d_out + (size_t)N * DD; // output 1: enc_feat_input

    // weight transposes (Wt[k][j] = W[j][k])
    for (int w = 0; w < 6; ++w)
        transpose128<<<64, 256, 0, stream>>>(Wm[w], Wt + (size_t)w * 16384);

    // CSR by dst
    hipMemsetAsync(deg, 0, (size_t)N * 4, stream);
    hist_kernel<<<(E + 255) / 256, 256, 0, stream>>>(edst, deg, E);
    scan_kernel<<<1, 1024, 0, stream>>>(deg, rowptr, cursor, N);
    scatter_kernel<<<(E + 255) / 256, 256, 0, stream>>>(esrc, edst, cursor, csr_src, E);

    int gb = (N + DD - 1) / DD;
    int sb = (N + 3) / 4;

    // layer 0
    gemm_kernel<1><<<gb, 512, 0, stream>>>(x, Wt + 0 * 16384, nullptr, nullptr, bpool0, m, N);
    segmax_kernel<<<sb, 256, 0, stream>>>(m, rowptr, csr_src, agg, N);
    gemm_kernel<2><<<gb, 512, 0, stream>>>(x, Wt + 1 * 16384, agg, Wt + 2 * 16384, b0, out_enc, N);

    // layer 1
    gemm_kernel<1><<<gb, 512, 0, stream>>>(out_enc, Wt + 3 * 16384, nullptr, nullptr, bpool1, m, N);
    segmax_kernel<<<sb, 256, 0, stream>>>(m, rowptr, csr_src, agg, N);
    gemm_kernel<0><<<gb, 512, 0, stream>>>(out_enc, Wt + 4 * 16384, agg, Wt + 5 * 16384, b1, out_h, N);
}

// Round 2
// 368.136 us; speedup vs baseline: 1.5416x; 1.5416x over previous
//
#include <hip/hip_runtime.h>
#include <hip/hip_fp16.h>

#define DD 128

typedef __attribute__((ext_vector_type(8))) short bf16x8;
typedef __attribute__((ext_vector_type(4))) float f32x4;

static __device__ __forceinline__ ushort f2bf(float f) {
    unsigned u = __float_as_uint(f);
    u = u + 0x7FFF + ((u >> 16) & 1);   // RNE
    return (ushort)(u >> 16);
}
static __device__ __forceinline__ float bf2f(ushort h) {
    return __uint_as_float(((unsigned)h) << 16);
}

// ---------------- weights -> bf16 hi/lo split ----------------
__global__ void prep_w(const float* __restrict__ W0, const float* __restrict__ W1,
                       const float* __restrict__ W2, const float* __restrict__ W3,
                       const float* __restrict__ W4, const float* __restrict__ W5,
                       ushort* __restrict__ Whi, ushort* __restrict__ Wlo) {
    int idx = blockIdx.x * 256 + threadIdx.x;   // 0 .. 6*16384-1
    int wi = idx >> 14;
    int off = idx & 16383;
    float a;
    switch (wi) {
        case 0: a = W0[off]; break;
        case 1: a = W1[off]; break;
        case 2: a = W2[off]; break;
        case 3: a = W3[off]; break;
        case 4: a = W4[off]; break;
        default: a = W5[off]; break;
    }
    ushort h = f2bf(a);
    Whi[idx] = h;
    Wlo[idx] = f2bf(a - bf2f(h));
}

// ---------------- histogram of dst ----------------
__global__ void hist_kernel(const int* __restrict__ dst, int* __restrict__ deg, int E) {
    int e = blockIdx.x * 256 + threadIdx.x;
    if (e < E) atomicAdd(&deg[dst[e]], 1);
}

// ---------------- single-block scan: rowptr + cursor ----------------
__global__ __launch_bounds__(1024) void scan_kernel(const int* __restrict__ deg,
                                                    int* __restrict__ rowptr,
                                                    int* __restrict__ cursor, int n) {
    __shared__ int s[1024];
    __shared__ int carry_s;
    int t = threadIdx.x;
    if (t == 0) { carry_s = 0; rowptr[0] = 0; }
    __syncthreads();
    for (int base = 0; base < n; base += 8192) {
        int i0 = base + t * 8;
        int v[8];
        int sum = 0;
#pragma unroll
        for (int u = 0; u < 8; ++u) {
            v[u] = (i0 + u < n) ? deg[i0 + u] : 0;
            sum += v[u];
        }
        s[t] = sum;
        __syncthreads();
        for (int off = 1; off < 1024; off <<= 1) {
            int x = (t >= off) ? s[t - off] : 0;
            __syncthreads();
            s[t] += x;
            __syncthreads();
        }
        int carryv = carry_s;
        int run = s[t] - sum + carryv;
#pragma unroll
        for (int u = 0; u < 8; ++u) {
            int i = i0 + u;
            if (i < n) {
                cursor[i] = run;
                run += v[u];
                rowptr[i + 1] = run;
            }
        }
        __syncthreads();
        if (t == 1023) carry_s = s[1023] + carryv;
        __syncthreads();
    }
}

// ---------------- scatter edges into CSR buckets ----------------
__global__ void scatter_kernel(const int* __restrict__ src, const int* __restrict__ dst,
                               int* __restrict__ cursor, int* __restrict__ csr_src, int E) {
    int e = blockIdx.x * 256 + threadIdx.x;
    if (e < E) {
        int p = atomicAdd(&cursor[dst[e]], 1);
        csr_src[p] = src[e];
    }
}

// ---------------- segment max gather (half rows), 4-deep ILP ----------------
__global__ __launch_bounds__(256) void segmax_half(const __half* __restrict__ m,
                                                   const int* __restrict__ rowptr,
                                                   const int* __restrict__ csr_src,
                                                   __half* __restrict__ agg, int n) {
    int node = blockIdx.x * 4 + (threadIdx.x >> 6);
    if (node >= n) return;
    int lane = threadIdx.x & 63;
    int beg = rowptr[node], end = rowptr[node + 1];
    const __half* mp = m + lane * 2;
    float2 a = make_float2(0.f, 0.f), b = a, c = a, d = a;  // relu'd inputs >= 0
    int e = beg;
    for (; e + 4 <= end; e += 4) {
        int s0 = csr_src[e], s1 = csr_src[e + 1], s2 = csr_src[e + 2], s3 = csr_src[e + 3];
        float2 v0 = __half22float2(*(const __half2*)(mp + (size_t)s0 * DD));
        float2 v1 = __half22float2(*(const __half2*)(mp + (size_t)s1 * DD));
        float2 v2 = __half22float2(*(const __half2*)(mp + (size_t)s2 * DD));
        float2 v3 = __half22float2(*(const __half2*)(mp + (size_t)s3 * DD));
        a.x = fmaxf(a.x, v0.x); a.y = fmaxf(a.y, v0.y);
        b.x = fmaxf(b.x, v1.x); b.y = fmaxf(b.y, v1.y);
        c.x = fmaxf(c.x, v2.x); c.y = fmaxf(c.y, v2.y);
        d.x = fmaxf(d.x, v3.x); d.y = fmaxf(d.y, v3.y);
    }
    for (; e < end; ++e) {
        int s0 = csr_src[e];
        float2 v0 = __half22float2(*(const __half2*)(mp + (size_t)s0 * DD));
        a.x = fmaxf(a.x, v0.x); a.y = fmaxf(a.y, v0.y);
    }
    a.x = fmaxf(fmaxf(a.x, b.x), fmaxf(c.x, d.x));
    a.y = fmaxf(fmaxf(a.y, b.y), fmaxf(c.y, d.y));
    *(__half2*)(agg + (size_t)node * DD + lane * 2) = __float22half2_rn(a);
}

// ---------------- MFMA GEMM: out = A@WA^T (+ G@WG^T) + bias ----------------
// split-bf16: X = hi + lo; X*W ~= hi*Whi + lo*Whi + hi*Wlo  (error ~2^-16 rel)
// EPI: 0 = none (f32 out), 1 = relu (half out), 2 = relu + row-L2-norm (f32 out)
template <int EPI, bool FUSED>
__global__ __launch_bounds__(256, 2) void gemm_mfma(
    const float* __restrict__ A, const ushort* __restrict__ WAhi, const ushort* __restrict__ WAlo,
    const __half* __restrict__ G, const ushort* __restrict__ WGhi, const ushort* __restrict__ WGlo,
    const float* __restrict__ bias, void* __restrict__ outv, int nrows) {
    extern __shared__ char smem[];
    int tid = threadIdx.x;
    int lane = tid & 63;
    int w = tid >> 6;
    int l16 = lane & 15;
    int lg = lane >> 4;
    int koff = lg * 8;
    int blk0 = blockIdx.x * 128;
    int rbase = blk0 + w * 32;

    f32x4 zero4 = {0.f, 0.f, 0.f, 0.f};
    f32x4 acc[2][8];
#pragma unroll
    for (int mt = 0; mt < 2; ++mt)
#pragma unroll
        for (int nt = 0; nt < 8; ++nt) acc[mt][nt] = zero4;

    // ---- pass 1: A (f32) ----
#pragma unroll
    for (int kk = 0; kk < 4; ++kk) {
        int k0 = kk * 32 + koff;
        bf16x8 ah[2], al[2];
#pragma unroll
        for (int mt = 0; mt < 2; ++mt) {
            int row = rbase + mt * 16 + l16;
            float va[8];
            if (row < nrows) {
                float4 v0 = *(const float4*)(A + (size_t)row * DD + k0);
                float4 v1 = *(const float4*)(A + (size_t)row * DD + k0 + 4);
                va[0] = v0.x; va[1] = v0.y; va[2] = v0.z; va[3] = v0.w;
                va[4] = v1.x; va[5] = v1.y; va[6] = v1.z; va[7] = v1.w;
            } else {
#pragma unroll
                for (int j = 0; j < 8; ++j) va[j] = 0.f;
            }
#pragma unroll
            for (int j = 0; j < 8; ++j) {
                ushort h = f2bf(va[j]);
                ah[mt][j] = (short)h;
                al[mt][j] = (short)f2bf(va[j] - bf2f(h));
            }
        }
#pragma unroll
        for (int nt = 0; nt < 8; ++nt) {
            bf16x8 wh = *(const bf16x8*)(WAhi + (size_t)(nt * 16 + l16) * DD + k0);
            bf16x8 wl = *(const bf16x8*)(WAlo + (size_t)(nt * 16 + l16) * DD + k0);
#pragma unroll
            for (int mt = 0; mt < 2; ++mt) {
                acc[mt][nt] = __builtin_amdgcn_mfma_f32_16x16x32_bf16(ah[mt], wh, acc[mt][nt], 0, 0, 0);
                acc[mt][nt] = __builtin_amdgcn_mfma_f32_16x16x32_bf16(al[mt], wh, acc[mt][nt], 0, 0, 0);
                acc[mt][nt] = __builtin_amdgcn_mfma_f32_16x16x32_bf16(ah[mt], wl, acc[mt][nt], 0, 0, 0);
            }
        }
    }

    // ---- pass 2: G (half) ----
    if constexpr (FUSED) {
#pragma unroll
        for (int kk = 0; kk < 4; ++kk) {
            int k0 = kk * 32 + koff;
            bf16x8 gh[2], gl[2];
#pragma unroll
            for (int mt = 0; mt < 2; ++mt) {
                int row = rbase + mt * 16 + l16;
                float va[8];
                if (row < nrows) {
                    union { bf16x8 v; __half h[8]; } u;
                    u.v = *(const bf16x8*)(G + (size_t)row * DD + k0);
#pragma unroll
                    for (int j = 0; j < 8; ++j) va[j] = __half2float(u.h[j]);
                } else {
#pragma unroll
                    for (int j = 0; j < 8; ++j) va[j] = 0.f;
                }
#pragma unroll
                for (int j = 0; j < 8; ++j) {
                    ushort h = f2bf(va[j]);
                    gh[mt][j] = (short)h;
                    gl[mt][j] = (short)f2bf(va[j] - bf2f(h));
                }
            }
#pragma unroll
            for (int nt = 0; nt < 8; ++nt) {
                bf16x8 wh = *(const bf16x8*)(WGhi + (size_t)(nt * 16 + l16) * DD + k0);
                bf16x8 wl = *(const bf16x8*)(WGlo + (size_t)(nt * 16 + l16) * DD + k0);
#pragma unroll
                for (int mt = 0; mt < 2; ++mt) {
                    acc[mt][nt] = __builtin_amdgcn_mfma_f32_16x16x32_bf16(gh[mt], wh, acc[mt][nt], 0, 0, 0);
                    acc[mt][nt] = __builtin_amdgcn_mfma_f32_16x16x32_bf16(gl[mt], wh, acc[mt][nt], 0, 0, 0);
                    acc[mt][nt] = __builtin_amdgcn_mfma_f32_16x16x32_bf16(gh[mt], wl, acc[mt][nt], 0, 0, 0);
                }
            }
        }
    }

    // ---- epilogue: bias (+relu)(+l2norm), LDS repack, coalesced store ----
    float bv[8];
#pragma unroll
    for (int nt = 0; nt < 8; ++nt) bv[nt] = bias[nt * 16 + l16];

    if constexpr (EPI == 1) {
        __half* lds = (__half*)smem;
#pragma unroll
        for (int mt = 0; mt < 2; ++mt)
#pragma unroll
            for (int r = 0; r < 4; ++r) {
                int lr = w * 32 + mt * 16 + lg * 4 + r;
#pragma unroll
                for (int nt = 0; nt < 8; ++nt) {
                    float v = fmaxf(acc[mt][nt][r] + bv[nt], 0.f);
                    lds[lr * DD + nt * 16 + l16] = __float2half(v);
                }
            }
        __syncthreads();
        __half* o = (__half*)outv;
#pragma unroll
        for (int it = 0; it < 8; ++it) {
            int idx = it * 256 + tid;
            int r = idx >> 4, cc = idx & 15;
            int row = blk0 + r;
            if (row < nrows)
                *(bf16x8*)(o + (size_t)row * DD + cc * 8) = *(const bf16x8*)(lds + r * DD + cc * 8);
        }
    } else {
        float* lds = (float*)smem;
#pragma unroll
        for (int mt = 0; mt < 2; ++mt)
#pragma unroll
            for (int r = 0; r < 4; ++r) {
                int lr = w * 32 + mt * 16 + lg * 4 + r;
                float vv[8];
                float s = 0.f;
#pragma unroll
                for (int nt = 0; nt < 8; ++nt) {
                    float v = acc[mt][nt][r] + bv[nt];
                    if (EPI == 2) v = fmaxf(v, 0.f);
                    vv[nt] = v;
                    s += v * v;
                }
                if (EPI == 2) {
                    s += __shfl_xor(s, 1);
                    s += __shfl_xor(s, 2);
                    s += __shfl_xor(s, 4);
                    s += __shfl_xor(s, 8);
                    float sc = 1.f / fmaxf(sqrtf(s), 1e-12f);
#pragma unroll
                    for (int nt = 0; nt < 8; ++nt) vv[nt] *= sc;
                }
#pragma unroll
                for (int nt = 0; nt < 8; ++nt) lds[lr * DD + nt * 16 + l16] = vv[nt];
            }
        __syncthreads();
        float* o = (float*)outv;
#pragma unroll
        for (int it = 0; it < 16; ++it) {
            int idx = it * 256 + tid;
            int r = idx >> 5, cc = idx & 31;
            int row = blk0 + r;
            if (row < nrows)
                *(f32x4*)(o + (size_t)row * DD + cc * 4) = *(const f32x4*)(lds + r * DD + cc * 4);
        }
    }
}

static inline size_t align16(size_t x) { return (x + 15) & ~(size_t)15; }

extern "C" void kernel_launch(void* const* d_in, const int* in_sizes, int n_in,
                              void* d_out, int out_size, void* d_ws, size_t ws_size,
                              hipStream_t stream) {
    const float* x  = (const float*)d_in[0];
    const int* esrc = (const int*)d_in[1];
    const int* edst = (const int*)d_in[2];
    const float* Wm[6];
    for (int i = 0; i < 6; ++i) Wm[i] = (const float*)d_in[3 + i];
    const float* bpool0 = (const float*)d_in[9];
    const float* b0     = (const float*)d_in[10];
    const float* bpool1 = (const float*)d_in[11];
    const float* b1     = (const float*)d_in[12];

    int N = in_sizes[0] / DD;
    int E = in_sizes[1];

    // workspace layout
    char* p = (char*)d_ws;
    ushort* Whi  = (ushort*)p; p += align16((size_t)6 * 16384 * 2);
    ushort* Wlo  = (ushort*)p; p += align16((size_t)6 * 16384 * 2);
    __half* m    = (__half*)p; p += align16((size_t)N * DD * 2);
    __half* agg  = (__half*)p; p += align16((size_t)N * DD * 2);
    int* deg     = (int*)p;    p += align16((size_t)N * 4);
    int* rowptr  = (int*)p;    p += align16((size_t)(N + 1) * 4);
    int* cursor  = (int*)p;    p += align16((size_t)N * 4);
    int* csr_src = (int*)p;    p += align16((size_t)E * 4);

    float* out_h   = (float*)d_out;                  // output 0: final layer
    float* out_enc = (float*)d_out + (size_t)N * DD; // output 1: enc_feat_input

    // prep: weight bf16 hi/lo split + CSR by dst
    prep_w<<<384, 256, 0, stream>>>(Wm[0], Wm[1], Wm[2], Wm[3], Wm[4], Wm[5], Whi, Wlo);
    hipMemsetAsync(deg, 0, (size_t)N * 4, stream);
    hist_kernel<<<(E + 255) / 256, 256, 0, stream>>>(edst, deg, E);
    scan_kernel<<<1, 1024, 0, stream>>>(deg, rowptr, cursor, N);
    scatter_kernel<<<(E + 255) / 256, 256, 0, stream>>>(esrc, edst, cursor, csr_src, E);

    int gb = (N + 127) / 128;
    int sb = (N + 3) / 4;

    // layer 0
    gemm_mfma<1, false><<<gb, 256, 32768, stream>>>(x, Whi + 0 * 16384, Wlo + 0 * 16384,
                                                    nullptr, nullptr, nullptr, bpool0, m, N);
    segmax_half<<<sb, 256, 0, stream>>>(m, rowptr, csr_src, agg, N);
    gemm_mfma<2, true><<<gb, 256, 65536, stream>>>(x, Whi + 1 * 16384, Wlo + 1 * 16384,
                                                   agg, Whi + 2 * 16384, Wlo + 2 * 16384, b0, out_enc, N);

    // layer 1
    gemm_mfma<1, false><<<gb, 256, 32768, stream>>>(out_enc, Whi + 3 * 16384, Wlo + 3 * 16384,
                                                    nullptr, nullptr, nullptr, bpool1, m, N);
    segmax_half<<<sb, 256, 0, stream>>>(m, rowptr, csr_src, agg, N);
    gemm_mfma<0, true><<<gb, 256, 65536, stream>>>(out_enc, Whi + 4 * 16384, Wlo + 4 * 16384,
                                                   agg, Whi + 5 * 16384, Wlo + 5 * 16384, b1, out_h, N);
}

// Round 3
// 315.117 us; speedup vs baseline: 1.8010x; 1.1683x over previous
//
#include <hip/hip_runtime.h>
#include <hip/hip_fp16.h>

#define DD 128
#define SCAN_T 1024
#define SCAN_E 8
#define SCAN_CHUNK (SCAN_T * SCAN_E)   // 8192

typedef __attribute__((ext_vector_type(8))) short bf16x8;
typedef __attribute__((ext_vector_type(4))) float f32x4;

static __device__ __forceinline__ ushort f2bf(float f) {
    unsigned u = __float_as_uint(f);
    u = u + 0x7FFF + ((u >> 16) & 1);   // RNE
    return (ushort)(u >> 16);
}
static __device__ __forceinline__ float bf2f(ushort h) {
    return __uint_as_float(((unsigned)h) << 16);
}

// ---------------- weights -> bf16 hi/lo split ----------------
__global__ void prep_w(const float* __restrict__ W0, const float* __restrict__ W1,
                       const float* __restrict__ W2, const float* __restrict__ W3,
                       const float* __restrict__ W4, const float* __restrict__ W5,
                       ushort* __restrict__ Whi, ushort* __restrict__ Wlo) {
    int idx = blockIdx.x * 256 + threadIdx.x;   // 0 .. 6*16384-1
    int wi = idx >> 14;
    int off = idx & 16383;
    float a;
    switch (wi) {
        case 0: a = W0[off]; break;
        case 1: a = W1[off]; break;
        case 2: a = W2[off]; break;
        case 3: a = W3[off]; break;
        case 4: a = W4[off]; break;
        default: a = W5[off]; break;
    }
    ushort h = f2bf(a);
    Whi[idx] = h;
    Wlo[idx] = f2bf(a - bf2f(h));
}

// ---------------- histogram of dst ----------------
__global__ void hist_kernel(const int* __restrict__ dst, int* __restrict__ deg, int E) {
    int e = blockIdx.x * 256 + threadIdx.x;
    if (e < E) atomicAdd(&deg[dst[e]], 1);
}

// ---------------- multi-block scan, phase 1: per-chunk sums ----------------
__global__ __launch_bounds__(SCAN_T) void partial_reduce(const int* __restrict__ deg,
                                                         int* __restrict__ bsum, int n) {
    __shared__ int s[SCAN_T];
    int t = threadIdx.x;
    int i0 = blockIdx.x * SCAN_CHUNK + t * SCAN_E;
    int sum = 0;
#pragma unroll
    for (int u = 0; u < SCAN_E; ++u) {
        int i = i0 + u;
        sum += (i < n) ? deg[i] : 0;
    }
    s[t] = sum;
    __syncthreads();
    for (int off = SCAN_T / 2; off > 0; off >>= 1) {
        if (t < off) s[t] += s[t + off];
        __syncthreads();
    }
    if (t == 0) bsum[blockIdx.x] = s[0];
}

// ---------------- multi-block scan, phase 2: per-chunk scan with carry ----------------
__global__ __launch_bounds__(SCAN_T) void block_scan(const int* __restrict__ deg,
                                                     const int* __restrict__ bsum,
                                                     int* __restrict__ rowptr,
                                                     int* __restrict__ cursor, int n) {
    __shared__ int s[SCAN_T];
    int t = threadIdx.x;
    int b = blockIdx.x;
    int carry = 0;
    for (int k = 0; k < b; ++k) carry += bsum[k];   // few blocks; cheap, uniform
    if (b == 0 && t == 0) rowptr[0] = 0;

    int i0 = b * SCAN_CHUNK + t * SCAN_E;
    int v[SCAN_E];
    int sum = 0;
#pragma unroll
    for (int u = 0; u < SCAN_E; ++u) {
        v[u] = (i0 + u < n) ? deg[i0 + u] : 0;
        sum += v[u];
    }
    s[t] = sum;
    __syncthreads();
    for (int off = 1; off < SCAN_T; off <<= 1) {
        int x = (t >= off) ? s[t - off] : 0;
        __syncthreads();
        s[t] += x;
        __syncthreads();
    }
    int run = s[t] - sum + carry;   // exclusive prefix of this thread's first elem
#pragma unroll
    for (int u = 0; u < SCAN_E; ++u) {
        int i = i0 + u;
        if (i < n) {
            cursor[i] = run;
            run += v[u];
            rowptr[i + 1] = run;
        }
    }
}

// ---------------- scatter edges into CSR buckets ----------------
__global__ void scatter_kernel(const int* __restrict__ src, const int* __restrict__ dst,
                               int* __restrict__ cursor, int* __restrict__ csr_src, int E) {
    int e = blockIdx.x * 256 + threadIdx.x;
    if (e < E) {
        int p = atomicAdd(&cursor[dst[e]], 1);
        csr_src[p] = src[e];
    }
}

// ---------------- segment max gather (half rows), 4-deep ILP ----------------
__global__ __launch_bounds__(256) void segmax_half(const __half* __restrict__ m,
                                                   const int* __restrict__ rowptr,
                                                   const int* __restrict__ csr_src,
                                                   __half* __restrict__ agg, int n) {
    int node = blockIdx.x * 4 + (threadIdx.x >> 6);
    if (node >= n) return;
    int lane = threadIdx.x & 63;
    int beg = rowptr[node], end = rowptr[node + 1];
    const __half* mp = m + lane * 2;
    float2 a = make_float2(0.f, 0.f), b = a, c = a, d = a;  // relu'd inputs >= 0
    int e = beg;
    for (; e + 4 <= end; e += 4) {
        int s0 = csr_src[e], s1 = csr_src[e + 1], s2 = csr_src[e + 2], s3 = csr_src[e + 3];
        float2 v0 = __half22float2(*(const __half2*)(mp + (size_t)s0 * DD));
        float2 v1 = __half22float2(*(const __half2*)(mp + (size_t)s1 * DD));
        float2 v2 = __half22float2(*(const __half2*)(mp + (size_t)s2 * DD));
        float2 v3 = __half22float2(*(const __half2*)(mp + (size_t)s3 * DD));
        a.x = fmaxf(a.x, v0.x); a.y = fmaxf(a.y, v0.y);
        b.x = fmaxf(b.x, v1.x); b.y = fmaxf(b.y, v1.y);
        c.x = fmaxf(c.x, v2.x); c.y = fmaxf(c.y, v2.y);
        d.x = fmaxf(d.x, v3.x); d.y = fmaxf(d.y, v3.y);
    }
    for (; e < end; ++e) {
        int s0 = csr_src[e];
        float2 v0 = __half22float2(*(const __half2*)(mp + (size_t)s0 * DD));
        a.x = fmaxf(a.x, v0.x); a.y = fmaxf(a.y, v0.y);
    }
    a.x = fmaxf(fmaxf(a.x, b.x), fmaxf(c.x, d.x));
    a.y = fmaxf(fmaxf(a.y, b.y), fmaxf(c.y, d.y));
    *(__half2*)(agg + (size_t)node * DD + lane * 2) = __float22half2_rn(a);
}

// ---------------- MFMA GEMM: out = A@WA^T (+ G@WG^T) + bias ----------------
// split-bf16: X = hi + lo; X*W ~= hi*Whi + lo*Whi + hi*Wlo  (error ~2^-16 rel)
// EPI: 0 = none (f32 out), 1 = relu (half out), 2 = relu + row-L2-norm (f32 out)
template <int EPI, bool FUSED>
__global__ __launch_bounds__(256, 2) void gemm_mfma(
    const float* __restrict__ A, const ushort* __restrict__ WAhi, const ushort* __restrict__ WAlo,
    const __half* __restrict__ G, const ushort* __restrict__ WGhi, const ushort* __restrict__ WGlo,
    const float* __restrict__ bias, void* __restrict__ outv, int nrows) {
    extern __shared__ char smem[];
    int tid = threadIdx.x;
    int lane = tid & 63;
    int w = tid >> 6;
    int l16 = lane & 15;
    int lg = lane >> 4;
    int koff = lg * 8;
    int blk0 = blockIdx.x * 128;
    int rbase = blk0 + w * 32;

    f32x4 zero4 = {0.f, 0.f, 0.f, 0.f};
    f32x4 acc[2][8];
#pragma unroll
    for (int mt = 0; mt < 2; ++mt)
#pragma unroll
        for (int nt = 0; nt < 8; ++nt) acc[mt][nt] = zero4;

    // ---- pass 1: A (f32) ----
#pragma unroll
    for (int kk = 0; kk < 4; ++kk) {
        int k0 = kk * 32 + koff;
        bf16x8 ah[2], al[2];
#pragma unroll
        for (int mt = 0; mt < 2; ++mt) {
            int row = rbase + mt * 16 + l16;
            float va[8];
            if (row < nrows) {
                float4 v0 = *(const float4*)(A + (size_t)row * DD + k0);
                float4 v1 = *(const float4*)(A + (size_t)row * DD + k0 + 4);
                va[0] = v0.x; va[1] = v0.y; va[2] = v0.z; va[3] = v0.w;
                va[4] = v1.x; va[5] = v1.y; va[6] = v1.z; va[7] = v1.w;
            } else {
#pragma unroll
                for (int j = 0; j < 8; ++j) va[j] = 0.f;
            }
#pragma unroll
            for (int j = 0; j < 8; ++j) {
                ushort h = f2bf(va[j]);
                ah[mt][j] = (short)h;
                al[mt][j] = (short)f2bf(va[j] - bf2f(h));
            }
        }
#pragma unroll
        for (int nt = 0; nt < 8; ++nt) {
            bf16x8 wh = *(const bf16x8*)(WAhi + (size_t)(nt * 16 + l16) * DD + k0);
            bf16x8 wl = *(const bf16x8*)(WAlo + (size_t)(nt * 16 + l16) * DD + k0);
#pragma unroll
            for (int mt = 0; mt < 2; ++mt) {
                acc[mt][nt] = __builtin_amdgcn_mfma_f32_16x16x32_bf16(ah[mt], wh, acc[mt][nt], 0, 0, 0);
                acc[mt][nt] = __builtin_amdgcn_mfma_f32_16x16x32_bf16(al[mt], wh, acc[mt][nt], 0, 0, 0);
                acc[mt][nt] = __builtin_amdgcn_mfma_f32_16x16x32_bf16(ah[mt], wl, acc[mt][nt], 0, 0, 0);
            }
        }
    }

    // ---- pass 2: G (half) ----
    if constexpr (FUSED) {
#pragma unroll
        for (int kk = 0; kk < 4; ++kk) {
            int k0 = kk * 32 + koff;
            bf16x8 gh[2], gl[2];
#pragma unroll
            for (int mt = 0; mt < 2; ++mt) {
                int row = rbase + mt * 16 + l16;
                float va[8];
                if (row < nrows) {
                    union { bf16x8 v; __half h[8]; } u;
                    u.v = *(const bf16x8*)(G + (size_t)row * DD + k0);
#pragma unroll
                    for (int j = 0; j < 8; ++j) va[j] = __half2float(u.h[j]);
                } else {
#pragma unroll
                    for (int j = 0; j < 8; ++j) va[j] = 0.f;
                }
#pragma unroll
                for (int j = 0; j < 8; ++j) {
                    ushort h = f2bf(va[j]);
                    gh[mt][j] = (short)h;
                    gl[mt][j] = (short)f2bf(va[j] - bf2f(h));
                }
            }
#pragma unroll
            for (int nt = 0; nt < 8; ++nt) {
                bf16x8 wh = *(const bf16x8*)(WGhi + (size_t)(nt * 16 + l16) * DD + k0);
                bf16x8 wl = *(const bf16x8*)(WGlo + (size_t)(nt * 16 + l16) * DD + k0);
#pragma unroll
                for (int mt = 0; mt < 2; ++mt) {
                    acc[mt][nt] = __builtin_amdgcn_mfma_f32_16x16x32_bf16(gh[mt], wh, acc[mt][nt], 0, 0, 0);
                    acc[mt][nt] = __builtin_amdgcn_mfma_f32_16x16x32_bf16(gl[mt], wh, acc[mt][nt], 0, 0, 0);
                    acc[mt][nt] = __builtin_amdgcn_mfma_f32_16x16x32_bf16(gh[mt], wl, acc[mt][nt], 0, 0, 0);
                }
            }
        }
    }

    // ---- epilogue: bias (+relu)(+l2norm), LDS repack, coalesced store ----
    float bv[8];
#pragma unroll
    for (int nt = 0; nt < 8; ++nt) bv[nt] = bias[nt * 16 + l16];

    if constexpr (EPI == 1) {
        __half* lds = (__half*)smem;
#pragma unroll
        for (int mt = 0; mt < 2; ++mt)
#pragma unroll
            for (int r = 0; r < 4; ++r) {
                int lr = w * 32 + mt * 16 + lg * 4 + r;
#pragma unroll
                for (int nt = 0; nt < 8; ++nt) {
                    float v = fmaxf(acc[mt][nt][r] + bv[nt], 0.f);
                    lds[lr * DD + nt * 16 + l16] = __float2half(v);
                }
            }
        __syncthreads();
        __half* o = (__half*)outv;
#pragma unroll
        for (int it = 0; it < 8; ++it) {
            int idx = it * 256 + tid;
            int r = idx >> 4, cc = idx & 15;
            int row = blk0 + r;
            if (row < nrows)
                *(bf16x8*)(o + (size_t)row * DD + cc * 8) = *(const bf16x8*)(lds + r * DD + cc * 8);
        }
    } else {
        float* lds = (float*)smem;
#pragma unroll
        for (int mt = 0; mt < 2; ++mt)
#pragma unroll
            for (int r = 0; r < 4; ++r) {
                int lr = w * 32 + mt * 16 + lg * 4 + r;
                float vv[8];
                float s = 0.f;
#pragma unroll
                for (int nt = 0; nt < 8; ++nt) {
                    float v = acc[mt][nt][r] + bv[nt];
                    if (EPI == 2) v = fmaxf(v, 0.f);
                    vv[nt] = v;
                    s += v * v;
                }
                if (EPI == 2) {
                    s += __shfl_xor(s, 1);
                    s += __shfl_xor(s, 2);
                    s += __shfl_xor(s, 4);
                    s += __shfl_xor(s, 8);
                    float sc = 1.f / fmaxf(sqrtf(s), 1e-12f);
#pragma unroll
                    for (int nt = 0; nt < 8; ++nt) vv[nt] *= sc;
                }
#pragma unroll
                for (int nt = 0; nt < 8; ++nt) lds[lr * DD + nt * 16 + l16] = vv[nt];
            }
        __syncthreads();
        float* o = (float*)outv;
#pragma unroll
        for (int it = 0; it < 16; ++it) {
            int idx = it * 256 + tid;
            int r = idx >> 5, cc = idx & 31;
            int row = blk0 + r;
            if (row < nrows)
                *(f32x4*)(o + (size_t)row * DD + cc * 4) = *(const f32x4*)(lds + r * DD + cc * 4);
        }
    }
}

static inline size_t align16(size_t x) { return (x + 15) & ~(size_t)15; }

extern "C" void kernel_launch(void* const* d_in, const int* in_sizes, int n_in,
                              void* d_out, int out_size, void* d_ws, size_t ws_size,
                              hipStream_t stream) {
    const float* x  = (const float*)d_in[0];
    const int* esrc = (const int*)d_in[1];
    const int* edst = (const int*)d_in[2];
    const float* Wm[6];
    for (int i = 0; i < 6; ++i) Wm[i] = (const float*)d_in[3 + i];
    const float* bpool0 = (const float*)d_in[9];
    const float* b0     = (const float*)d_in[10];
    const float* bpool1 = (const float*)d_in[11];
    const float* b1     = (const float*)d_in[12];

    int N = in_sizes[0] / DD;
    int E = in_sizes[1];
    int nsb = (N + SCAN_CHUNK - 1) / SCAN_CHUNK;   // scan blocks (7 for N=50000)

    // workspace layout
    char* p = (char*)d_ws;
    ushort* Whi  = (ushort*)p; p += align16((size_t)6 * 16384 * 2);
    ushort* Wlo  = (ushort*)p; p += align16((size_t)6 * 16384 * 2);
    __half* m    = (__half*)p; p += align16((size_t)N * DD * 2);
    __half* agg  = (__half*)p; p += align16((size_t)N * DD * 2);
    int* deg     = (int*)p;    p += align16((size_t)N * 4);
    int* rowptr  = (int*)p;    p += align16((size_t)(N + 1) * 4);
    int* cursor  = (int*)p;    p += align16((size_t)N * 4);
    int* bsum    = (int*)p;    p += align16((size_t)nsb * 4);
    int* csr_src = (int*)p;    p += align16((size_t)E * 4);

    float* out_h   = (float*)d_out;                  // output 0: final layer
    float* out_enc = (float*)d_out + (size_t)N * DD; // output 1: enc_feat_input

    // prep: weight bf16 hi/lo split + CSR by dst
    prep_w<<<384, 256, 0, stream>>>(Wm[0], Wm[1], Wm[2], Wm[3], Wm[4], Wm[5], Whi, Wlo);
    hipMemsetAsync(deg, 0, (size_t)N * 4, stream);
    hist_kernel<<<(E + 255) / 256, 256, 0, stream>>>(edst, deg, E);
    partial_reduce<<<nsb, SCAN_T, 0, stream>>>(deg, bsum, N);
    block_scan<<<nsb, SCAN_T, 0, stream>>>(deg, bsum, rowptr, cursor, N);
    scatter_kernel<<<(E + 255) / 256, 256, 0, stream>>>(esrc, edst, cursor, csr_src, E);

    int gb = (N + 127) / 128;
    int sb = (N + 3) / 4;

    // layer 0
    gemm_mfma<1, false><<<gb, 256, 32768, stream>>>(x, Whi + 0 * 16384, Wlo + 0 * 16384,
                                                    nullptr, nullptr, nullptr, bpool0, m, N);
    segmax_half<<<sb, 256, 0, stream>>>(m, rowptr, csr_src, agg, N);
    gemm_mfma<2, true><<<gb, 256, 65536, stream>>>(x, Whi + 1 * 16384, Wlo + 1 * 16384,
                                                   agg, Whi + 2 * 16384, Wlo + 2 * 16384, b0, out_enc, N);

    // layer 1
    gemm_mfma<1, false><<<gb, 256, 32768, stream>>>(out_enc, Whi + 3 * 16384, Wlo + 3 * 16384,
                                                    nullptr, nullptr, nullptr, bpool1, m, N);
    segmax_half<<<sb, 256, 0, stream>>>(m, rowptr, csr_src, agg, N);
    gemm_mfma<0, true><<<gb, 256, 65536, stream>>>(out_enc, Whi + 4 * 16384, Wlo + 4 * 16384,
                                                   agg, Whi + 5 * 16384, Wlo + 5 * 16384, b1, out_h, N);
}